// Round 16
// baseline (373.830 us; speedup 1.0000x reference)
//
#include <hip/hip_runtime.h>

// VQ: N=262144 rows, DIM=64, K=1024 codes.
// Single fused compute kernel, HIGH-OCCUPANCY variant:
//   16 rows/wave (ONE A-set, ~52 VGPR -> below the 64-VGPR occupancy cliff,
//   launch_bounds(256,8)). 16x16x32 bf16 MFMA, 3-product hi/lo split,
//   acc init = ||e||^2 + 256 (positive scores -> raw bits order-preserving),
//   key = (bits & ~63) | ct; top2 via v_med3_u32 (3 ops/score).
//   B tiles from L2, sequential order, compiler unroll-2. Winner publish +
//   gather fully in-wave via shfl (no LDS, no barriers). Rows with top2
//   margin < FLAG_EPS (~0.15%) exactly re-solved in-wave (fp32).
// np.argmin first-min tie-break preserved (ct in key LSBs + residue
//   tie-break; near-ties re-solved exactly with index-ordered selection).

#define VQ_N 262144
#define VQ_DIM 64
#define VQ_K 1024
#define NT 64                   // 64 code-tiles of 16 codes
#define TCH 128                 // 16B chunks per hi (or lo) tile = 2048 B
#define FLAG_EPS 1.2e-2f

typedef short short8 __attribute__((ext_vector_type(8)));
typedef float f32x4 __attribute__((ext_vector_type(4)));

// ws layout (bytes)
#define WS_BH    0                   // 131072 (e hi fragments)
#define WS_BL    (128*1024)          // 131072 (e lo fragments)
#define WS_E2    (256*1024)          // float[1024] raw ||e||^2 (resolve)
#define WS_E2P   (260*1024)          // float[1024] ||e||^2 + 256 (scan init)
#define WS_NEEDED (264*1024)

static __device__ __forceinline__ unsigned short f2bf_rtne(float f) {
    unsigned u = __float_as_uint(f);
    unsigned r = u + 0x7FFFu + ((u >> 16) & 1u);
    return (unsigned short)(r >> 16);
}
static __device__ __forceinline__ float bf2f(unsigned short h) {
    return __uint_as_float(((unsigned)h) << 16);
}
static __device__ __forceinline__ unsigned med3u(unsigned a, unsigned b, unsigned c) {
    unsigned d;
    asm("v_med3_u32 %0, %1, %2, %3" : "=v"(d) : "v"(a), "v"(b), "v"(c));
    return d;
}

// ---------------- prep: B fragments (hi/lo), e2, e2+256 ----------------
// chunk c = ct*128 + kc*64 + l : 8 bf16 of embed[ct*16+(l&15)][kc*32+(l>>4)*8+j]
__global__ void vq_prep(const float* __restrict__ embed, unsigned char* ws) {
    int t = blockIdx.x * 256 + threadIdx.x;     // 0 .. 17919
    if (t < 16384) {
        int arr = t >> 13;                      // 0 = hi, 1 = lo
        int c = t & 8191;
        int ct = c >> 7;
        int kc = (c >> 6) & 1;
        int l = c & 63;
        int code = ct * 16 + (l & 15);
        int kbase = kc * 32 + ((l >> 4) << 3);
        const float* ep = embed + (size_t)code * VQ_DIM + kbase;
        short8 pack;
#pragma unroll
        for (int j = 0; j < 8; ++j) {
            float v = ep[j];
            unsigned short h = f2bf_rtne(v);
            pack[j] = arr ? (short)f2bf_rtne(v - bf2f(h)) : (short)h;
        }
        ((short8*)(ws + (arr ? WS_BL : WS_BH)))[c] = pack;
    } else if (t < 16384 + VQ_K) {
        int code = t - 16384;
        const float* ep = embed + (size_t)code * VQ_DIM;
        float a0 = 0, a1 = 0, a2 = 0, a3 = 0;
#pragma unroll
        for (int j = 0; j < VQ_DIM; j += 4) {
            a0 = fmaf(ep[j], ep[j], a0);
            a1 = fmaf(ep[j + 1], ep[j + 1], a1);
            a2 = fmaf(ep[j + 2], ep[j + 2], a2);
            a3 = fmaf(ep[j + 3], ep[j + 3], a3);
        }
        float e2 = (a0 + a1) + (a2 + a3);
        ((float*)(ws + WS_E2))[code] = e2;
        ((float*)(ws + WS_E2P))[code] = e2 + 256.0f;
    }
}

// ---------------- stage 1: scan + in-wave gather + in-wave exact resolve ----------------
__global__ __launch_bounds__(256, 8)
void vq_stage1(const float* __restrict__ x, const float* __restrict__ embed,
               unsigned char* ws, float* __restrict__ out) {
    const int tid = threadIdx.x;
    const int lane = tid & 63;
    const int wave = tid >> 6;
    const int gwave = blockIdx.x * 4 + wave;   // owns 16 rows
    const int R0 = gwave * 16;
    const int g = lane >> 4;            // 0..3
    const int res = lane & 15;
    const int khalf = g << 3;           // A-frag k-offset within 32-chunk

    const short8* bh = (const short8*)(ws + WS_BH);
    const short8* bl = (const short8*)(ws + WS_BL);
    const float* e2g = (const float*)(ws + WS_E2);
    const float* e2p = (const float*)(ws + WS_E2P);

    // ---- A fragments: -2x hi/lo, ONE 16-row set ----
    short8 ah0, ah1, al0, al1;
#define MAKE_A(ROW, KC, AH, AL)                                             \
    {                                                                       \
        const float4* p4 = (const float4*)(x + (size_t)(ROW) * VQ_DIM +     \
                                           (KC) * 32 + khalf);              \
        float4 v0 = p4[0], v1 = p4[1];                                      \
        float q0 = -2.0f * v0.x, q1 = -2.0f * v0.y, q2 = -2.0f * v0.z,      \
              q3 = -2.0f * v0.w, q4 = -2.0f * v1.x, q5 = -2.0f * v1.y,      \
              q6 = -2.0f * v1.z, q7 = -2.0f * v1.w;                         \
        unsigned short h0 = f2bf_rtne(q0), h1 = f2bf_rtne(q1),              \
                       h2 = f2bf_rtne(q2), h3 = f2bf_rtne(q3),              \
                       h4 = f2bf_rtne(q4), h5 = f2bf_rtne(q5),              \
                       h6 = f2bf_rtne(q6), h7 = f2bf_rtne(q7);              \
        AH[0] = (short)h0; AH[1] = (short)h1; AH[2] = (short)h2;            \
        AH[3] = (short)h3; AH[4] = (short)h4; AH[5] = (short)h5;            \
        AH[6] = (short)h6; AH[7] = (short)h7;                               \
        AL[0] = (short)f2bf_rtne(q0 - bf2f(h0));                            \
        AL[1] = (short)f2bf_rtne(q1 - bf2f(h1));                            \
        AL[2] = (short)f2bf_rtne(q2 - bf2f(h2));                            \
        AL[3] = (short)f2bf_rtne(q3 - bf2f(h3));                            \
        AL[4] = (short)f2bf_rtne(q4 - bf2f(h4));                            \
        AL[5] = (short)f2bf_rtne(q5 - bf2f(h5));                            \
        AL[6] = (short)f2bf_rtne(q6 - bf2f(h6));                            \
        AL[7] = (short)f2bf_rtne(q7 - bf2f(h7));                            \
    }
    const int row0 = R0 + res;
    MAKE_A(row0, 0, ah0, al0)
    MAKE_A(row0, 1, ah1, al1)
#undef MAKE_A

    unsigned m1k[4], m2k[4];
#pragma unroll
    for (int r = 0; r < 4; ++r) { m1k[r] = 0xFFFFFFFFu; m2k[r] = 0xFFFFFFFFu; }

    // ---- main scan: 3-product, sequential tiles, compiler unroll-2 ----
#pragma unroll 2
    for (int ct = 0; ct < NT; ++ct) {
        const short8* bht = bh + (size_t)ct * TCH;
        const short8* blt = bl + (size_t)ct * TCH;
        short8 bh0 = bht[lane];
        short8 bh1 = bht[64 + lane];
        short8 bl0 = blt[lane];
        short8 bl1 = blt[64 + lane];
        float e2c = e2p[ct * 16 + res];
        unsigned ctu = (unsigned)ct;

        f32x4 acc = {e2c, e2c, e2c, e2c};
        acc = __builtin_amdgcn_mfma_f32_16x16x32_bf16(al0, bh0, acc, 0, 0, 0);
        acc = __builtin_amdgcn_mfma_f32_16x16x32_bf16(al1, bh1, acc, 0, 0, 0);
        acc = __builtin_amdgcn_mfma_f32_16x16x32_bf16(ah0, bl0, acc, 0, 0, 0);
        acc = __builtin_amdgcn_mfma_f32_16x16x32_bf16(ah1, bl1, acc, 0, 0, 0);
        acc = __builtin_amdgcn_mfma_f32_16x16x32_bf16(ah0, bh0, acc, 0, 0, 0);
        acc = __builtin_amdgcn_mfma_f32_16x16x32_bf16(ah1, bh1, acc, 0, 0, 0);

        // top2 update: key gen + med3 + min = 3 ops/score
#pragma unroll
        for (int r = 0; r < 4; ++r) {
            unsigned key = (__float_as_uint(acc[r]) & 0xFFFFFFC0u) | ctu;
            m2k[r] = med3u(m1k[r], m2k[r], key);
            m1k[r] = m1k[r] < key ? m1k[r] : key;
        }
    }

    // ---- reduce over the 16 codes (lanes within each 16-group) ----
    unsigned res0[4];
#pragma unroll
    for (int r = 0; r < 4; ++r) res0[r] = (unsigned)res;
#pragma unroll
    for (int m = 1; m <= 8; m <<= 1) {
#pragma unroll
        for (int r = 0; r < 4; ++r) {
            unsigned ok = (unsigned)__shfl_xor((int)m1k[r], m);
            unsigned ok2 = (unsigned)__shfl_xor((int)m2k[r], m);
            unsigned orr = (unsigned)__shfl_xor((int)res0[r], m);
            unsigned t1 = m1k[r] > ok ? m1k[r] : ok;
            unsigned c2 = ok2 < t1 ? ok2 : t1;
            m2k[r] = m2k[r] < c2 ? m2k[r] : c2;
            bool take = (ok < m1k[r]) || (ok == m1k[r] && orr < res0[r]);
            if (take) { m1k[r] = ok; res0[r] = orr; }
        }
    }

    // ---- winner codes + margin flags (all lanes of a group agree) ----
    int code0[4];
    unsigned fmask = 0;
#pragma unroll
    for (int r = 0; r < 4; ++r) {
        code0[r] = (int)((m1k[r] & 63u) * 16u + res0[r]);
        float s1 = __uint_as_float(m1k[r] & 0xFFFFFFC0u);
        float s2 = __uint_as_float(m2k[r] & 0xFFFFFFC0u);
        if (s2 - s1 < FLAG_EPS) fmask |= 1u << (4 * g + r);
    }
    fmask |= (unsigned)__shfl_xor((int)fmask, 16);
    fmask |= (unsigned)__shfl_xor((int)fmask, 32);
    unsigned wmask = fmask;             // 16-bit flag mask on every lane

    // ---- in-wave gather: lane handles row q = lane>>2, chunk = lane&3 ----
    {
        const int q = lane >> 2;            // 0..15
        const int gq = q >> 2;              // source group
        const int rq = q & 3;
        const int src = gq << 4;
        int a0 = __shfl(code0[0], src), a1 = __shfl(code0[1], src);
        int a2 = __shfl(code0[2], src), a3 = __shfl(code0[3], src);
        int my = (rq == 0) ? a0 : (rq == 1) ? a1 : (rq == 2) ? a2 : a3;
        const float4* ep = (const float4*)(embed + (size_t)my * VQ_DIM) + (lane & 3) * 4;
        float4* op = (float4*)(out + (size_t)(R0 + q) * VQ_DIM) + (lane & 3) * 4;
#pragma unroll
        for (int j = 0; j < 4; ++j) op[j] = ep[j];
    }

    // ---- in-wave exact fp32 re-solve of flagged rows (~0.15%) ----
    while (wmask) {
        int b = __ffs(wmask) - 1;
        wmask &= wmask - 1;
        int row = R0 + b;
        const float4* xr4 = (const float4*)(x + (size_t)row * VQ_DIM);
        float best = __builtin_inff();
        int bi = VQ_K;
        for (int t = 0; t < VQ_K / 64; ++t) {
            int c = t * 64 + lane;
            const float4* ep4 = (const float4*)(embed + (size_t)c * VQ_DIM);
            float a0 = 0, a1 = 0, a2 = 0, a3 = 0;
#pragma unroll
            for (int j = 0; j < VQ_DIM / 4; ++j) {
                float4 xv = xr4[j];
                float4 ev = ep4[j];
                a0 = fmaf(xv.x, ev.x, a0);
                a1 = fmaf(xv.y, ev.y, a1);
                a2 = fmaf(xv.z, ev.z, a2);
                a3 = fmaf(xv.w, ev.w, a3);
            }
            float dot = (a0 + a1) + (a2 + a3);
            float s = fmaf(-2.0f, dot, e2g[c]);
            if (s < best || (s == best && c < bi)) { best = s; bi = c; }
        }
#pragma unroll
        for (int m = 1; m <= 32; m <<= 1) {
            float ob = __shfl_xor(best, m);
            int oi = __shfl_xor(bi, m);
            if (ob < best || (ob == best && oi < bi)) { best = ob; bi = oi; }
        }
        out[(size_t)row * VQ_DIM + lane] = embed[(size_t)bi * VQ_DIM + lane];
    }
}

// ---------------- fallback (round-1 fp32, only if ws too small) ----------------
__global__ __launch_bounds__(256, 4)
void vq_fallback(const float* __restrict__ x, const float* __restrict__ embed,
                 float* __restrict__ out) {
    __shared__ float e2s[VQ_K];
    const int tid = threadIdx.x;
    for (int c = tid; c < VQ_K; c += 256) {
        const float4* ep = (const float4*)(embed + c * VQ_DIM);
        float s = 0.0f;
#pragma unroll
        for (int j = 0; j < VQ_DIM / 4; ++j) {
            float4 v = ep[j];
            s = fmaf(v.x, v.x, s); s = fmaf(v.y, v.y, s);
            s = fmaf(v.z, v.z, s); s = fmaf(v.w, v.w, s);
        }
        e2s[c] = s;
    }
    __syncthreads();
    const int row = blockIdx.x * 256 + tid;
    float xr[VQ_DIM];
    const float4* xp = (const float4*)(x + (size_t)row * VQ_DIM);
#pragma unroll
    for (int j = 0; j < VQ_DIM / 4; ++j) {
        float4 v = xp[j];
        xr[4 * j] = v.x; xr[4 * j + 1] = v.y; xr[4 * j + 2] = v.z; xr[4 * j + 3] = v.w;
    }
    float best = __builtin_inff();
    int bidx = 0;
    for (int c = 0; c < VQ_K; ++c) {
        const float4* ep = (const float4*)(embed + c * VQ_DIM);
        float a0 = 0, a1 = 0, a2 = 0, a3 = 0;
#pragma unroll
        for (int j = 0; j < VQ_DIM / 4; ++j) {
            float4 v = ep[j];
            a0 = fmaf(xr[4 * j], v.x, a0);
            a1 = fmaf(xr[4 * j + 1], v.y, a1);
            a2 = fmaf(xr[4 * j + 2], v.z, a2);
            a3 = fmaf(xr[4 * j + 3], v.w, a3);
        }
        float score = fmaf(-2.0f, (a0 + a1) + (a2 + a3), e2s[c]);
        if (score < best) { best = score; bidx = c; }
    }
    const float4* bp = (const float4*)(embed + (size_t)bidx * VQ_DIM);
    float4* op = (float4*)(out + (size_t)row * VQ_DIM);
#pragma unroll
    for (int j = 0; j < VQ_DIM / 4; ++j) op[j] = bp[j];
}

extern "C" void kernel_launch(void* const* d_in, const int* in_sizes, int n_in,
                              void* d_out, int out_size, void* d_ws, size_t ws_size,
                              hipStream_t stream) {
    const float* x = (const float*)d_in[0];
    const float* embed = (const float*)d_in[1];
    float* out = (float*)d_out;
    if (ws_size < WS_NEEDED) {
        hipLaunchKernelGGL(vq_fallback, dim3(VQ_N / 256), dim3(256), 0, stream, x, embed, out);
        return;
    }
    unsigned char* ws = (unsigned char*)d_ws;
    hipLaunchKernelGGL(vq_prep, dim3(70), dim3(256), 0, stream, embed, ws);
    hipLaunchKernelGGL(vq_stage1, dim3(VQ_N / 64), dim3(256), 0, stream, x, embed, ws, out);
}

// Round 18
// 171.261 us; speedup vs baseline: 2.1828x; 2.1828x over previous
//
#include <hip/hip_runtime.h>

// VQ: N=262144 rows, DIM=64, K=1024 codes.
// FINAL (champion, R15): single fused compute kernel, zero-LDS:
//   16x16x32 bf16 MFMA, 3-product hi/lo split (xl.eh + xh.el + xh.eh),
//   acc init = ||e||^2 + 256 (positive scores -> raw bits order-preserving),
//   key = (bits & ~63) | ct; top2 via v_med3_u32 (3 ops/score).
//   32 rows/wave, two 16-row A-sets share each B read; B tiles from L2,
//   sequential order, compiler unroll-2. Winner publish + gather fully
//   in-wave via shfl (no LDS, no barriers). Rows with top2 margin <
//   FLAG_EPS (~0.15%) exactly re-solved in-wave (fp32, no reg array).
// np.argmin first-min tie-break preserved (ct in key LSBs + residue
//   tie-break; near-ties re-solved exactly with index-ordered selection).

#define VQ_N 262144
#define VQ_DIM 64
#define VQ_K 1024
#define NT 64                   // 64 code-tiles of 16 codes
#define TCH 128                 // 16B chunks per hi (or lo) tile = 2048 B
#define FLAG_EPS 1.2e-2f

typedef short short8 __attribute__((ext_vector_type(8)));
typedef float f32x4 __attribute__((ext_vector_type(4)));

// ws layout (bytes)
#define WS_BH    0                   // 131072 (e hi fragments)
#define WS_BL    (128*1024)          // 131072 (e lo fragments)
#define WS_E2    (256*1024)          // float[1024] raw ||e||^2 (resolve)
#define WS_E2P   (260*1024)          // float[1024] ||e||^2 + 256 (scan init)
#define WS_NEEDED (264*1024)

static __device__ __forceinline__ unsigned short f2bf_rtne(float f) {
    unsigned u = __float_as_uint(f);
    unsigned r = u + 0x7FFFu + ((u >> 16) & 1u);
    return (unsigned short)(r >> 16);
}
static __device__ __forceinline__ float bf2f(unsigned short h) {
    return __uint_as_float(((unsigned)h) << 16);
}
static __device__ __forceinline__ unsigned med3u(unsigned a, unsigned b, unsigned c) {
    unsigned d;
    asm("v_med3_u32 %0, %1, %2, %3" : "=v"(d) : "v"(a), "v"(b), "v"(c));
    return d;
}

// ---------------- prep: B fragments (hi/lo), e2, e2+256 ----------------
// chunk c = ct*128 + kc*64 + l : 8 bf16 of embed[ct*16+(l&15)][kc*32+(l>>4)*8+j]
__global__ void vq_prep(const float* __restrict__ embed, unsigned char* ws) {
    int t = blockIdx.x * 256 + threadIdx.x;     // 0 .. 17919
    if (t < 16384) {
        int arr = t >> 13;                      // 0 = hi, 1 = lo
        int c = t & 8191;
        int ct = c >> 7;
        int kc = (c >> 6) & 1;
        int l = c & 63;
        int code = ct * 16 + (l & 15);
        int kbase = kc * 32 + ((l >> 4) << 3);
        const float* ep = embed + (size_t)code * VQ_DIM + kbase;
        short8 pack;
#pragma unroll
        for (int j = 0; j < 8; ++j) {
            float v = ep[j];
            unsigned short h = f2bf_rtne(v);
            pack[j] = arr ? (short)f2bf_rtne(v - bf2f(h)) : (short)h;
        }
        ((short8*)(ws + (arr ? WS_BL : WS_BH)))[c] = pack;
    } else if (t < 16384 + VQ_K) {
        int code = t - 16384;
        const float* ep = embed + (size_t)code * VQ_DIM;
        float a0 = 0, a1 = 0, a2 = 0, a3 = 0;
#pragma unroll
        for (int j = 0; j < VQ_DIM; j += 4) {
            a0 = fmaf(ep[j], ep[j], a0);
            a1 = fmaf(ep[j + 1], ep[j + 1], a1);
            a2 = fmaf(ep[j + 2], ep[j + 2], a2);
            a3 = fmaf(ep[j + 3], ep[j + 3], a3);
        }
        float e2 = (a0 + a1) + (a2 + a3);
        ((float*)(ws + WS_E2))[code] = e2;
        ((float*)(ws + WS_E2P))[code] = e2 + 256.0f;
    }
}

// ---------------- stage 1: scan + in-wave gather + in-wave exact resolve ----------------
__global__ __launch_bounds__(256, 4)
void vq_stage1(const float* __restrict__ x, const float* __restrict__ embed,
               unsigned char* ws, float* __restrict__ out) {
    const int tid = threadIdx.x;
    const int lane = tid & 63;
    const int wave = tid >> 6;
    const int gwave = blockIdx.x * 4 + wave;   // owns 32 rows
    const int R0 = gwave * 32;
    const int g = lane >> 4;            // 0..3
    const int res = lane & 15;
    const int khalf = g << 3;           // A-frag k-offset within 32-chunk

    const short8* bh = (const short8*)(ws + WS_BH);
    const short8* bl = (const short8*)(ws + WS_BL);
    const float* e2g = (const float*)(ws + WS_E2);
    const float* e2p = (const float*)(ws + WS_E2P);

    // ---- A fragments: -2x hi/lo, two 16-row sets, named scalars ----
    short8 ah00, ah01, al00, al01, ah10, ah11, al10, al11;
#define MAKE_A(ROW, KC, AH, AL)                                             \
    {                                                                       \
        const float4* p4 = (const float4*)(x + (size_t)(ROW) * VQ_DIM +     \
                                           (KC) * 32 + khalf);              \
        float4 v0 = p4[0], v1 = p4[1];                                      \
        float q0 = -2.0f * v0.x, q1 = -2.0f * v0.y, q2 = -2.0f * v0.z,      \
              q3 = -2.0f * v0.w, q4 = -2.0f * v1.x, q5 = -2.0f * v1.y,      \
              q6 = -2.0f * v1.z, q7 = -2.0f * v1.w;                         \
        unsigned short h0 = f2bf_rtne(q0), h1 = f2bf_rtne(q1),              \
                       h2 = f2bf_rtne(q2), h3 = f2bf_rtne(q3),              \
                       h4 = f2bf_rtne(q4), h5 = f2bf_rtne(q5),              \
                       h6 = f2bf_rtne(q6), h7 = f2bf_rtne(q7);              \
        AH[0] = (short)h0; AH[1] = (short)h1; AH[2] = (short)h2;            \
        AH[3] = (short)h3; AH[4] = (short)h4; AH[5] = (short)h5;            \
        AH[6] = (short)h6; AH[7] = (short)h7;                               \
        AL[0] = (short)f2bf_rtne(q0 - bf2f(h0));                            \
        AL[1] = (short)f2bf_rtne(q1 - bf2f(h1));                            \
        AL[2] = (short)f2bf_rtne(q2 - bf2f(h2));                            \
        AL[3] = (short)f2bf_rtne(q3 - bf2f(h3));                            \
        AL[4] = (short)f2bf_rtne(q4 - bf2f(h4));                            \
        AL[5] = (short)f2bf_rtne(q5 - bf2f(h5));                            \
        AL[6] = (short)f2bf_rtne(q6 - bf2f(h6));                            \
        AL[7] = (short)f2bf_rtne(q7 - bf2f(h7));                            \
    }
    const int row0 = R0 + res;
    const int row1 = row0 + 16;
    MAKE_A(row0, 0, ah00, al00)
    MAKE_A(row0, 1, ah01, al01)
    MAKE_A(row1, 0, ah10, al10)
    MAKE_A(row1, 1, ah11, al11)
#undef MAKE_A

    unsigned m1k0[4], m2k0[4], m1k1[4], m2k1[4];
#pragma unroll
    for (int r = 0; r < 4; ++r) {
        m1k0[r] = 0xFFFFFFFFu; m2k0[r] = 0xFFFFFFFFu;
        m1k1[r] = 0xFFFFFFFFu; m2k1[r] = 0xFFFFFFFFu;
    }

    // ---- main scan: 3-product, sequential tiles, compiler unroll-2 ----
#pragma unroll 2
    for (int ct = 0; ct < NT; ++ct) {
        const short8* bht = bh + (size_t)ct * TCH;
        const short8* blt = bl + (size_t)ct * TCH;
        short8 bh0 = bht[lane];
        short8 bh1 = bht[64 + lane];
        short8 bl0 = blt[lane];
        short8 bl1 = blt[64 + lane];
        float e2c = e2p[ct * 16 + res];
        unsigned ctu = (unsigned)ct;

        f32x4 acc0 = {e2c, e2c, e2c, e2c};
        acc0 = __builtin_amdgcn_mfma_f32_16x16x32_bf16(al00, bh0, acc0, 0, 0, 0);
        acc0 = __builtin_amdgcn_mfma_f32_16x16x32_bf16(al01, bh1, acc0, 0, 0, 0);
        acc0 = __builtin_amdgcn_mfma_f32_16x16x32_bf16(ah00, bl0, acc0, 0, 0, 0);
        acc0 = __builtin_amdgcn_mfma_f32_16x16x32_bf16(ah01, bl1, acc0, 0, 0, 0);
        acc0 = __builtin_amdgcn_mfma_f32_16x16x32_bf16(ah00, bh0, acc0, 0, 0, 0);
        acc0 = __builtin_amdgcn_mfma_f32_16x16x32_bf16(ah01, bh1, acc0, 0, 0, 0);

        f32x4 acc1 = {e2c, e2c, e2c, e2c};
        acc1 = __builtin_amdgcn_mfma_f32_16x16x32_bf16(al10, bh0, acc1, 0, 0, 0);
        acc1 = __builtin_amdgcn_mfma_f32_16x16x32_bf16(al11, bh1, acc1, 0, 0, 0);
        acc1 = __builtin_amdgcn_mfma_f32_16x16x32_bf16(ah10, bl0, acc1, 0, 0, 0);
        acc1 = __builtin_amdgcn_mfma_f32_16x16x32_bf16(ah11, bl1, acc1, 0, 0, 0);
        acc1 = __builtin_amdgcn_mfma_f32_16x16x32_bf16(ah10, bh0, acc1, 0, 0, 0);
        acc1 = __builtin_amdgcn_mfma_f32_16x16x32_bf16(ah11, bh1, acc1, 0, 0, 0);

        // top2 update: key gen (v_and_or) + med3 + min = 3 ops/score
#pragma unroll
        for (int r = 0; r < 4; ++r) {
            unsigned key = (__float_as_uint(acc0[r]) & 0xFFFFFFC0u) | ctu;
            m2k0[r] = med3u(m1k0[r], m2k0[r], key);
            m1k0[r] = m1k0[r] < key ? m1k0[r] : key;
        }
#pragma unroll
        for (int r = 0; r < 4; ++r) {
            unsigned key = (__float_as_uint(acc1[r]) & 0xFFFFFFC0u) | ctu;
            m2k1[r] = med3u(m1k1[r], m2k1[r], key);
            m1k1[r] = m1k1[r] < key ? m1k1[r] : key;
        }
    }

    // ---- reduce over the 16 codes (lanes within each 16-group) ----
    unsigned res0[4], res1[4];
#pragma unroll
    for (int r = 0; r < 4; ++r) { res0[r] = (unsigned)res; res1[r] = res0[r]; }
#define RED_STEP(M1, M2, RES, m)                                                      \
    {                                                                                 \
        _Pragma("unroll")                                                             \
        for (int r = 0; r < 4; ++r) {                                                 \
            unsigned ok = (unsigned)__shfl_xor((int)M1[r], m);                        \
            unsigned ok2 = (unsigned)__shfl_xor((int)M2[r], m);                       \
            unsigned orr = (unsigned)__shfl_xor((int)RES[r], m);                      \
            unsigned t1 = M1[r] > ok ? M1[r] : ok;                                    \
            unsigned c2 = ok2 < t1 ? ok2 : t1;                                        \
            M2[r] = M2[r] < c2 ? M2[r] : c2;                                          \
            bool take = (ok < M1[r]) || (ok == M1[r] && orr < RES[r]);                \
            if (take) { M1[r] = ok; RES[r] = orr; }                                   \
        }                                                                             \
    }
#pragma unroll
    for (int m = 1; m <= 8; m <<= 1) {
        RED_STEP(m1k0, m2k0, res0, m)
        RED_STEP(m1k1, m2k1, res1, m)
    }
#undef RED_STEP

    // ---- winner codes + margin flags (all lanes of a group agree) ----
    int code0[4], code1[4];
    unsigned fmask = 0;
#pragma unroll
    for (int r = 0; r < 4; ++r) {
        code0[r] = (int)((m1k0[r] & 63u) * 16u + res0[r]);
        code1[r] = (int)((m1k1[r] & 63u) * 16u + res1[r]);
        float s1a = __uint_as_float(m1k0[r] & 0xFFFFFFC0u);
        float s2a = __uint_as_float(m2k0[r] & 0xFFFFFFC0u);
        if (s2a - s1a < FLAG_EPS) fmask |= 1u << (4 * g + r);
        float s1b = __uint_as_float(m1k1[r] & 0xFFFFFFC0u);
        float s2b = __uint_as_float(m2k1[r] & 0xFFFFFFC0u);
        if (s2b - s1b < FLAG_EPS) fmask |= 1u << (16 + 4 * g + r);
    }
    fmask |= (unsigned)__shfl_xor((int)fmask, 16);
    fmask |= (unsigned)__shfl_xor((int)fmask, 32);
    unsigned wmask = fmask;             // full 32-row flag mask on every lane

    // ---- in-wave gather: lane handles row q = lane>>1, half = lane&1 ----
    {
        const int q = lane >> 1;            // 0..31
        const int setq = q >> 4;
        const int gq = (q & 15) >> 2;
        const int rq = q & 3;
        const int src = gq << 4;
        int a0 = __shfl(code0[0], src), a1 = __shfl(code0[1], src);
        int a2 = __shfl(code0[2], src), a3 = __shfl(code0[3], src);
        int b0 = __shfl(code1[0], src), b1 = __shfl(code1[1], src);
        int b2 = __shfl(code1[2], src), b3 = __shfl(code1[3], src);
        int cs0 = (rq == 0) ? a0 : (rq == 1) ? a1 : (rq == 2) ? a2 : a3;
        int cs1 = (rq == 0) ? b0 : (rq == 1) ? b1 : (rq == 2) ? b2 : b3;
        int my = setq ? cs1 : cs0;
        const float4* ep = (const float4*)(embed + (size_t)my * VQ_DIM) + (lane & 1) * 8;
        float4* op = (float4*)(out + (size_t)(R0 + q) * VQ_DIM) + (lane & 1) * 8;
#pragma unroll
        for (int j = 0; j < 8; ++j) op[j] = ep[j];
    }

    // ---- in-wave exact fp32 re-solve of flagged rows (~0.15%) ----
    while (wmask) {
        int b = __ffs(wmask) - 1;
        wmask &= wmask - 1;
        int row = R0 + b;
        const float4* xr4 = (const float4*)(x + (size_t)row * VQ_DIM);
        float best = __builtin_inff();
        int bi = VQ_K;
        for (int t = 0; t < VQ_K / 64; ++t) {
            int c = t * 64 + lane;
            const float4* ep4 = (const float4*)(embed + (size_t)c * VQ_DIM);
            float a0 = 0, a1 = 0, a2 = 0, a3 = 0;
#pragma unroll
            for (int j = 0; j < VQ_DIM / 4; ++j) {
                float4 xv = xr4[j];
                float4 ev = ep4[j];
                a0 = fmaf(xv.x, ev.x, a0);
                a1 = fmaf(xv.y, ev.y, a1);
                a2 = fmaf(xv.z, ev.z, a2);
                a3 = fmaf(xv.w, ev.w, a3);
            }
            float dot = (a0 + a1) + (a2 + a3);
            float s = fmaf(-2.0f, dot, e2g[c]);
            if (s < best || (s == best && c < bi)) { best = s; bi = c; }
        }
#pragma unroll
        for (int m = 1; m <= 32; m <<= 1) {
            float ob = __shfl_xor(best, m);
            int oi = __shfl_xor(bi, m);
            if (ob < best || (ob == best && oi < bi)) { best = ob; bi = oi; }
        }
        out[(size_t)row * VQ_DIM + lane] = embed[(size_t)bi * VQ_DIM + lane];
    }
}

// ---------------- fallback (round-1 fp32, only if ws too small) ----------------
__global__ __launch_bounds__(256, 4)
void vq_fallback(const float* __restrict__ x, const float* __restrict__ embed,
                 float* __restrict__ out) {
    __shared__ float e2s[VQ_K];
    const int tid = threadIdx.x;
    for (int c = tid; c < VQ_K; c += 256) {
        const float4* ep = (const float4*)(embed + c * VQ_DIM);
        float s = 0.0f;
#pragma unroll
        for (int j = 0; j < VQ_DIM / 4; ++j) {
            float4 v = ep[j];
            s = fmaf(v.x, v.x, s); s = fmaf(v.y, v.y, s);
            s = fmaf(v.z, v.z, s); s = fmaf(v.w, v.w, s);
        }
        e2s[c] = s;
    }
    __syncthreads();
    const int row = blockIdx.x * 256 + tid;
    float xr[VQ_DIM];
    const float4* xp = (const float4*)(x + (size_t)row * VQ_DIM);
#pragma unroll
    for (int j = 0; j < VQ_DIM / 4; ++j) {
        float4 v = xp[j];
        xr[4 * j] = v.x; xr[4 * j + 1] = v.y; xr[4 * j + 2] = v.z; xr[4 * j + 3] = v.w;
    }
    float best = __builtin_inff();
    int bidx = 0;
    for (int c = 0; c < VQ_K; ++c) {
        const float4* ep = (const float4*)(embed + c * VQ_DIM);
        float a0 = 0, a1 = 0, a2 = 0, a3 = 0;
#pragma unroll
        for (int j = 0; j < VQ_DIM / 4; ++j) {
            float4 v = ep[j];
            a0 = fmaf(xr[4 * j], v.x, a0);
            a1 = fmaf(xr[4 * j + 1], v.y, a1);
            a2 = fmaf(xr[4 * j + 2], v.z, a2);
            a3 = fmaf(xr[4 * j + 3], v.w, a3);
        }
        float score = fmaf(-2.0f, (a0 + a1) + (a2 + a3), e2s[c]);
        if (score < best) { best = score; bidx = c; }
    }
    const float4* bp = (const float4*)(embed + (size_t)bidx * VQ_DIM);
    float4* op = (float4*)(out + (size_t)row * VQ_DIM);
#pragma unroll
    for (int j = 0; j < VQ_DIM / 4; ++j) op[j] = bp[j];
}

extern "C" void kernel_launch(void* const* d_in, const int* in_sizes, int n_in,
                              void* d_out, int out_size, void* d_ws, size_t ws_size,
                              hipStream_t stream) {
    const float* x = (const float*)d_in[0];
    const float* embed = (const float*)d_in[1];
    float* out = (float*)d_out;
    if (ws_size < WS_NEEDED) {
        hipLaunchKernelGGL(vq_fallback, dim3(VQ_N / 256), dim3(256), 0, stream, x, embed, out);
        return;
    }
    unsigned char* ws = (unsigned char*)d_ws;
    hipLaunchKernelGGL(vq_prep, dim3(70), dim3(256), 0, stream, embed, ws);
    hipLaunchKernelGGL(vq_stage1, dim3(VQ_N / 128), dim3(256), 0, stream, x, embed, ws, out);
}